// Round 1
// baseline (1923.433 us; speedup 1.0000x reference)
//
#include <hip/hip_runtime.h>
#include <hip/hip_bf16.h>

// Problem constants
// B=8, NO=512, O=1024, H=16, DH=64
// M = B*NO = 4096 rows for all GEMMs, width 1024 per tensor part.
constexpr float ATT_SCALE = 0.125f;        // 1/sqrt(64)
constexpr float NEGS      = -1.25e8f;      // (-1e9) * SCALE, masked_fill happens BEFORE scale

// ---------------------------------------------------------------------------
// Generic fp32 tiled GEMM core: C[4096 x 1024-chunk] = op(A) @ W[:, wcol0:wcol0+64*gridx]
//  - A is split in up to 3 parts of [4096,1024] each (K = nparts*1024)
//  - optional relu on A load, optional per-row int mask multiply on store
//  - BM=128, BN=64, BK=16, 256 threads, 8x4 micro-tile
// ---------------------------------------------------------------------------
__device__ __forceinline__ void gemm_core(
    const float* __restrict__ A0, const float* __restrict__ A1, const float* __restrict__ A2,
    int K, bool relu,
    const float* __restrict__ W, int wld, int wcol0,
    const float* __restrict__ bias,           // already chunk-offset; indexed by local col
    const int* __restrict__ rowmask,          // nullptr if none; [4096]
    float* __restrict__ C)                    // ldc = 1024
{
  __shared__ float As[16][128];   // transposed A tile: As[k][m]
  __shared__ float Bs[16][64];

  const int tid = threadIdx.x;
  const int tr  = tid >> 4;        // 0..15 -> 8 rows each
  const int tc  = tid & 15;        // 0..15 -> 4 cols each
  const int m0  = blockIdx.y * 128;
  const int n0  = blockIdx.x * 64;

  // A-load mapping: each thread loads 8 consecutive k's of one row
  const int am  = tid >> 1;          // 0..127
  const int ak0 = (tid & 1) * 8;     // 0 or 8
  // B-load mapping: each thread loads 4 consecutive cols of one k-row
  const int bk  = tid >> 4;          // 0..15
  const int bn0 = (tid & 15) * 4;    // 0..60

  float acc[8][4] = {};
  float4 a0v, a1v, b4v;

  auto load_tile = [&](int k0) {
    const int part = k0 >> 10;                      // uniform: k0 multiple of 16
    const float* Ap = (part == 0) ? A0 : ((part == 1) ? A1 : A2);
    const float4* asrc = reinterpret_cast<const float4*>(
        Ap + (size_t)(m0 + am) * 1024 + ((k0 + ak0) & 1023));
    a0v = asrc[0];
    a1v = asrc[1];
    b4v = *reinterpret_cast<const float4*>(
        W + (size_t)(k0 + bk) * (size_t)wld + wcol0 + n0 + bn0);
  };

  load_tile(0);
  for (int k0 = 0; k0 < K; k0 += 16) {
    float4 aw0 = a0v, aw1 = a1v;
    if (relu) {
      aw0.x = fmaxf(aw0.x, 0.f); aw0.y = fmaxf(aw0.y, 0.f);
      aw0.z = fmaxf(aw0.z, 0.f); aw0.w = fmaxf(aw0.w, 0.f);
      aw1.x = fmaxf(aw1.x, 0.f); aw1.y = fmaxf(aw1.y, 0.f);
      aw1.z = fmaxf(aw1.z, 0.f); aw1.w = fmaxf(aw1.w, 0.f);
    }
    As[ak0 + 0][am] = aw0.x; As[ak0 + 1][am] = aw0.y;
    As[ak0 + 2][am] = aw0.z; As[ak0 + 3][am] = aw0.w;
    As[ak0 + 4][am] = aw1.x; As[ak0 + 5][am] = aw1.y;
    As[ak0 + 6][am] = aw1.z; As[ak0 + 7][am] = aw1.w;
    *reinterpret_cast<float4*>(&Bs[bk][bn0]) = b4v;
    __syncthreads();
    if (k0 + 16 < K) load_tile(k0 + 16);   // prefetch overlaps compute below
#pragma unroll
    for (int kk = 0; kk < 16; ++kk) {
      const float4 af0 = *reinterpret_cast<const float4*>(&As[kk][tr * 8]);
      const float4 af1 = *reinterpret_cast<const float4*>(&As[kk][tr * 8 + 4]);
      const float4 bf  = *reinterpret_cast<const float4*>(&Bs[kk][tc * 4]);
      const float a[8] = {af0.x, af0.y, af0.z, af0.w, af1.x, af1.y, af1.z, af1.w};
      const float b[4] = {bf.x, bf.y, bf.z, bf.w};
#pragma unroll
      for (int r = 0; r < 8; ++r)
#pragma unroll
        for (int c = 0; c < 4; ++c)
          acc[r][c] = fmaf(a[r], b[c], acc[r][c]);
    }
    __syncthreads();
  }

#pragma unroll
  for (int r = 0; r < 8; ++r) {
    const int row = m0 + tr * 8 + r;
    float rm = 1.0f;
    if (rowmask) rm = (float)rowmask[row];
    float4 o;
    o.x = (acc[r][0] + bias[n0 + tc * 4 + 0]) * rm;
    o.y = (acc[r][1] + bias[n0 + tc * 4 + 1]) * rm;
    o.z = (acc[r][2] + bias[n0 + tc * 4 + 2]) * rm;
    o.w = (acc[r][3] + bias[n0 + tc * 4 + 3]) * rm;
    *reinterpret_cast<float4*>(C + (size_t)row * 1024 + n0 + tc * 4) = o;
  }
}

// ---------------------------------------------------------------------------
// Projection kernel: computes the 5 needed 1024-wide chunks of
//   v_tr = (relu(v)@Wv+bv)*vm, q_tr, k_tr
// z: 0 -> v_q   (v, chunk 1)
//    1 -> q_k   (q, chunk 0)
//    2 -> q_v   (q, chunk 2)
//    3 -> k_k   (k, chunk 0)
//    4 -> k_q   (k, chunk 1)
// Output chunk z at ws + z*CH, CH = 4096*1024.
// ---------------------------------------------------------------------------
__global__ void __launch_bounds__(256) proj_kernel(
    const float* __restrict__ v, const float* __restrict__ q, const float* __restrict__ k,
    const int* __restrict__ vm, const int* __restrict__ qm, const int* __restrict__ km,
    const float* __restrict__ Wv, const float* __restrict__ bv,
    const float* __restrict__ Wq, const float* __restrict__ bq,
    const float* __restrict__ Wk, const float* __restrict__ bk,
    float* __restrict__ ws)
{
  const int z = blockIdx.z;
  const float* srcs[3]  = {v, q, k};
  const int*   msks[3]  = {vm, qm, km};
  const float* Ws[3]    = {Wv, Wq, Wk};
  const float* bs[3]    = {bv, bq, bk};
  const int src_idx[5]  = {0, 1, 1, 2, 2};
  const int chunk[5]    = {1, 0, 2, 0, 1};
  const int si = src_idx[z], ch = chunk[z];
  gemm_core(srcs[si], nullptr, nullptr, 1024, /*relu=*/true,
            Ws[si], 3072, ch * 1024, bs[si] + ch * 1024, msks[si],
            ws + (size_t)z * 4194304u);
}

// ---------------------------------------------------------------------------
// Output kernel:
// z=0: updated_v = [v | vq_update] @ Wvo + bvo           -> d_out + CH
// z=1: updated_V = [v | vq_update | vk_update] @ Wko+bko -> d_out
// ---------------------------------------------------------------------------
__global__ void __launch_bounds__(256) out_kernel(
    const float* __restrict__ v,
    const float* __restrict__ vq_upd, const float* __restrict__ vk_upd,
    const float* __restrict__ Wvo, const float* __restrict__ bvo,
    const float* __restrict__ Wko, const float* __restrict__ bko,
    float* __restrict__ out)
{
  const int z = blockIdx.z;
  const int K = (z == 0) ? 2048 : 3072;
  const float* W    = (z == 0) ? Wvo : Wko;
  const float* bias = (z == 0) ? bvo : bko;
  float* C = (z == 0) ? (out + 4194304u) : out;
  gemm_core(v, vq_upd, vk_upd, K, /*relu=*/false,
            W, 1024, 0, bias, nullptr, C);
}

// ---------------------------------------------------------------------------
// Flash-style fp32 attention.
// grid: (8 q-tiles of 64, H=16, B*2=16); z = b*2 + att
// att=0: Q=v_q, K=q_k, V=q_v, mask=q_mask -> vq_update (ws+5CH)
// att=1: Q=k_q, K=k_k, V=k_q, mask=k_mask -> vk_update (ws+6CH)
// 256 threads: QK mapping (ti,tj) covers 4x4 S sub-tile; PV mapping covers
// 4 rows x 4 d. P round-trips through the Ks LDS buffer (saves LDS).
// ---------------------------------------------------------------------------
__global__ void __launch_bounds__(256) attn_kernel(
    float* __restrict__ ws, const int* __restrict__ q_mask, const int* __restrict__ k_mask)
{
  constexpr size_t CH = (size_t)4096 * 1024;
  const int z = blockIdx.z;
  const int b = z >> 1, att = z & 1;
  const float *Q, *K, *V;
  const int* msk_g;
  float* O;
  if (att == 0) { Q = ws;          K = ws + CH;     V = ws + 2 * CH; msk_g = q_mask; O = ws + 5 * CH; }
  else          { Q = ws + 4 * CH; K = ws + 3 * CH; V = ws + 4 * CH; msk_g = k_mask; O = ws + 6 * CH; }

  const int h  = blockIdx.y;
  const int n0 = blockIdx.x * 64;

  __shared__ float Qs[64][68];
  __shared__ float Ks[64][68];   // reused to hold P after QK^T
  __shared__ float Vs[64][68];
  __shared__ int   msk[64];

  const int tid = threadIdx.x;
  const int li  = tid >> 2;           // load row 0..63
  const int ld0 = (tid & 3) * 16;     // load col group (16 floats)

  // Load Q tile [64][64] for this (b, h, q-tile)
  {
    const float* src = Q + (size_t)(b * 512 + n0 + li) * 1024 + h * 64 + ld0;
    const float4* s4 = reinterpret_cast<const float4*>(src);
    float4 t0 = s4[0], t1 = s4[1], t2 = s4[2], t3 = s4[3];
    *reinterpret_cast<float4*>(&Qs[li][ld0 + 0])  = t0;
    *reinterpret_cast<float4*>(&Qs[li][ld0 + 4])  = t1;
    *reinterpret_cast<float4*>(&Qs[li][ld0 + 8])  = t2;
    *reinterpret_cast<float4*>(&Qs[li][ld0 + 12]) = t3;
  }

  const int ti = tid >> 4, tj = tid & 15;
  const int i0 = ti * 4, j0 = tj * 4;

  float m[4], l[4], Oacc[4][4];
#pragma unroll
  for (int ii = 0; ii < 4; ++ii) {
    m[ii] = -3.0e38f; l[ii] = 0.f;
#pragma unroll
    for (int dd = 0; dd < 4; ++dd) Oacc[ii][dd] = 0.f;
  }

  for (int kt = 0; kt < 8; ++kt) {
    __syncthreads();   // prev PV reads done (and makes Q-load visible pattern safe)
    // Load K/V tiles (rows kt*64 .. +63)
    {
      const float* ksrc = K + (size_t)(b * 512 + kt * 64 + li) * 1024 + h * 64 + ld0;
      const float* vsrc = V + (size_t)(b * 512 + kt * 64 + li) * 1024 + h * 64 + ld0;
      const float4* k4 = reinterpret_cast<const float4*>(ksrc);
      const float4* v4 = reinterpret_cast<const float4*>(vsrc);
      float4 a = k4[0], bq4 = k4[1], c = k4[2], d = k4[3];
      float4 e = v4[0], f = v4[1], g = v4[2], hh = v4[3];
      *reinterpret_cast<float4*>(&Ks[li][ld0 + 0])  = a;
      *reinterpret_cast<float4*>(&Ks[li][ld0 + 4])  = bq4;
      *reinterpret_cast<float4*>(&Ks[li][ld0 + 8])  = c;
      *reinterpret_cast<float4*>(&Ks[li][ld0 + 12]) = d;
      *reinterpret_cast<float4*>(&Vs[li][ld0 + 0])  = e;
      *reinterpret_cast<float4*>(&Vs[li][ld0 + 4])  = f;
      *reinterpret_cast<float4*>(&Vs[li][ld0 + 8])  = g;
      *reinterpret_cast<float4*>(&Vs[li][ld0 + 12]) = hh;
      if (tid < 64) msk[tid] = msk_g[b * 512 + kt * 64 + tid];
    }
    __syncthreads();

    // S = Q K^T for this 4x4 sub-tile
    float s[4][4] = {};
#pragma unroll
    for (int d0 = 0; d0 < 64; d0 += 4) {
      float4 qf[4], kf[4];
#pragma unroll
      for (int ii = 0; ii < 4; ++ii) qf[ii] = *reinterpret_cast<const float4*>(&Qs[i0 + ii][d0]);
#pragma unroll
      for (int jj = 0; jj < 4; ++jj) kf[jj] = *reinterpret_cast<const float4*>(&Ks[j0 + jj][d0]);
#pragma unroll
      for (int ii = 0; ii < 4; ++ii)
#pragma unroll
        for (int jj = 0; jj < 4; ++jj)
          s[ii][jj] += qf[ii].x * kf[jj].x + qf[ii].y * kf[jj].y +
                       qf[ii].z * kf[jj].z + qf[ii].w * kf[jj].w;
    }

    // mask (before scale, per reference) then scale
    int mk[4];
#pragma unroll
    for (int jj = 0; jj < 4; ++jj) mk[jj] = msk[j0 + jj];
#pragma unroll
    for (int ii = 0; ii < 4; ++ii)
#pragma unroll
      for (int jj = 0; jj < 4; ++jj)
        s[ii][jj] = mk[jj] ? s[ii][jj] * ATT_SCALE : NEGS;

    // online softmax update (16 lanes per row group share identical state)
#pragma unroll
    for (int ii = 0; ii < 4; ++ii) {
      float tmax = fmaxf(fmaxf(s[ii][0], s[ii][1]), fmaxf(s[ii][2], s[ii][3]));
#pragma unroll
      for (int off = 1; off < 16; off <<= 1) tmax = fmaxf(tmax, __shfl_xor(tmax, off));
      const float newm = fmaxf(m[ii], tmax);
      const float corr = __expf(m[ii] - newm);
      float psum = 0.f;
#pragma unroll
      for (int jj = 0; jj < 4; ++jj) {
        const float p = __expf(s[ii][jj] - newm);
        s[ii][jj] = p;
        psum += p;
      }
#pragma unroll
      for (int off = 1; off < 16; off <<= 1) psum += __shfl_xor(psum, off);
      l[ii] = l[ii] * corr + psum;
      m[ii] = newm;
#pragma unroll
      for (int dd = 0; dd < 4; ++dd) Oacc[ii][dd] *= corr;
    }

    __syncthreads();   // all QK reads of Ks complete
    // stash P into the Ks buffer
#pragma unroll
    for (int ii = 0; ii < 4; ++ii)
      *reinterpret_cast<float4*>(&Ks[i0 + ii][j0]) =
          make_float4(s[ii][0], s[ii][1], s[ii][2], s[ii][3]);
    __syncthreads();

    // O += P @ V  (thread covers rows i0..i0+3, d-cols tj*4..+3)
#pragma unroll
    for (int jb = 0; jb < 64; jb += 4) {
      float4 pf[4], vf[4];
#pragma unroll
      for (int ii = 0; ii < 4; ++ii) pf[ii] = *reinterpret_cast<const float4*>(&Ks[i0 + ii][jb]);
#pragma unroll
      for (int jj = 0; jj < 4; ++jj) vf[jj] = *reinterpret_cast<const float4*>(&Vs[jb + jj][tj * 4]);
#pragma unroll
      for (int ii = 0; ii < 4; ++ii) {
        Oacc[ii][0] += pf[ii].x * vf[0].x + pf[ii].y * vf[1].x + pf[ii].z * vf[2].x + pf[ii].w * vf[3].x;
        Oacc[ii][1] += pf[ii].x * vf[0].y + pf[ii].y * vf[1].y + pf[ii].z * vf[2].y + pf[ii].w * vf[3].y;
        Oacc[ii][2] += pf[ii].x * vf[0].z + pf[ii].y * vf[1].z + pf[ii].z * vf[2].z + pf[ii].w * vf[3].z;
        Oacc[ii][3] += pf[ii].x * vf[0].w + pf[ii].y * vf[1].w + pf[ii].z * vf[2].w + pf[ii].w * vf[3].w;
      }
    }
  }

  // finalize: divide by l, store
#pragma unroll
  for (int ii = 0; ii < 4; ++ii) {
    const float inv = 1.0f / l[ii];
    const int row = b * 512 + n0 + i0 + ii;
    float4 o = make_float4(Oacc[ii][0] * inv, Oacc[ii][1] * inv,
                           Oacc[ii][2] * inv, Oacc[ii][3] * inv);
    *reinterpret_cast<float4*>(O + (size_t)row * 1024 + h * 64 + tj * 4) = o;
  }
}

// ---------------------------------------------------------------------------
extern "C" void kernel_launch(void* const* d_in, const int* in_sizes, int n_in,
                              void* d_out, int out_size, void* d_ws, size_t ws_size,
                              hipStream_t stream) {
  const float* v  = (const float*)d_in[0];
  const float* q  = (const float*)d_in[1];
  const float* k  = (const float*)d_in[2];
  const int* vm   = (const int*)d_in[3];
  const int* qm   = (const int*)d_in[4];
  const int* km   = (const int*)d_in[5];
  const float* Wv = (const float*)d_in[6];
  const float* bv = (const float*)d_in[7];
  const float* Wq = (const float*)d_in[8];
  const float* bq = (const float*)d_in[9];
  const float* Wk = (const float*)d_in[10];
  const float* bk = (const float*)d_in[11];
  const float* Wvo = (const float*)d_in[12];
  const float* bvo = (const float*)d_in[13];
  const float* Wko = (const float*)d_in[14];
  const float* bko = (const float*)d_in[15];
  float* ws  = (float*)d_ws;
  float* out = (float*)d_out;

  constexpr size_t CH = (size_t)4096 * 1024;

  // 1) projections: 5 needed chunks -> ws[0..5CH)
  proj_kernel<<<dim3(16, 32, 5), 256, 0, stream>>>(v, q, k, vm, qm, km,
                                                   Wv, bv, Wq, bq, Wk, bk, ws);
  // 2) both attentions -> vq_update (ws+5CH), vk_update (ws+6CH)
  attn_kernel<<<dim3(8, 16, 16), 256, 0, stream>>>(ws, qm, km);
  // 3) output projections -> d_out (updated_V first, then updated_v)
  out_kernel<<<dim3(16, 32, 2), 256, 0, stream>>>(v, ws + 5 * CH, ws + 6 * CH,
                                                  Wvo, bvo, Wko, bko, out);
}

// Round 4
// 514.531 us; speedup vs baseline: 3.7382x; 3.7382x over previous
//
#include <hip/hip_runtime.h>

// ---------------------------------------------------------------------------
// InterModalityUpdate: B=8, NO=512, O=1024, H=16, DH=64. M = 4096 rows.
// Strategy: split-bf16 (3xMFMA) emulated-fp32 GEMMs + single-bf16 MFMA attn.
// ---------------------------------------------------------------------------

typedef float  f32x4  __attribute__((ext_vector_type(4)));
typedef short  bf16x8 __attribute__((ext_vector_type(8)));
typedef unsigned short u16;
typedef unsigned short u16x8v __attribute__((ext_vector_type(8)));

constexpr float ATT_SCALE = 0.125f;     // 1/sqrt(64)
constexpr float NEGS      = -1.25e8f;   // (-1e9) * SCALE (mask applied before scale)

#define MiB (size_t(1) << 20)
// ---- workspace layout (bytes). Peak live = 108 MiB (< 112 MiB proven safe).
constexpr size_t O_VR_H = 0*MiB,  O_VR_L = 8*MiB;    // relu-split v (F-tiled)
constexpr size_t O_QR_H = 16*MiB, O_QR_L = 24*MiB;   // relu-split q
constexpr size_t O_KR_H = 32*MiB, O_KR_L = 40*MiB;   // relu-split k
constexpr size_t O_WP   = 48*MiB;                    // 5 proj W chunks: hi@48+4z, lo@50+4z
constexpr size_t O_PO   = 68*MiB;                    // proj outs bf16 row-major: z*8MiB
                                                     // {v_q,q_k,q_v,k_k,k_q}
constexpr size_t O_VT0  = 0*MiB,  O_VT1 = 8*MiB;     // q_v^T, k_q^T  [b][h][64d][512key]
constexpr size_t O_OVQ_H= 16*MiB, O_OVQ_L= 24*MiB;   // attn out vq split (F-tiled)
constexpr size_t O_OVK_H= 32*MiB, O_OVK_L= 40*MiB;   // attn out vk split
constexpr size_t O_V2_H = 48*MiB, O_V2_L = 56*MiB;   // v (no relu) split
constexpr size_t O_WVO_H= 64*MiB, O_WVO_L= 68*MiB;   // Wvo^T split (K=2048)
constexpr size_t O_WKO_H= 72*MiB, O_WKO_L= 78*MiB;   // Wko^T split (K=3072)

// ---- helpers ---------------------------------------------------------------
__device__ __forceinline__ u16 f2bf_rne(float x) {
  unsigned u = __float_as_uint(x);
  return (u16)((u + 0x7FFFu + ((u >> 16) & 1u)) >> 16);
}
__device__ __forceinline__ float bf2f(u16 h) {
  return __uint_as_float(((unsigned)h) << 16);
}
__device__ __forceinline__ void gload16(const void* g, void* l) {
  __builtin_amdgcn_global_load_lds(
      (const __attribute__((address_space(1))) unsigned int*)g,
      (__attribute__((address_space(3))) unsigned int*)l, 16, 0, 0);
}

// ---------------------------------------------------------------------------
// prep_act: fp32 [4096][1024] -> split bf16 hi/lo in F-tiled layout
//   F layout: chunk idx = ((rt*32 + kt)*4 + kg)*128 + r  holds 8 consecutive k.
// ---------------------------------------------------------------------------
__global__ __launch_bounds__(256) void prep_act(
    const float* __restrict__ s0, const float* __restrict__ s1, const float* __restrict__ s2,
    char* __restrict__ ws, const int relu,
    const size_t o0h, const size_t o0l, const size_t o1h, const size_t o1l,
    const size_t o2h, const size_t o2l)
{
  const int z = blockIdx.z;
  const float* src = (z == 0) ? s0 : (z == 1) ? s1 : s2;
  u16* dh = (u16*)(ws + ((z == 0) ? o0h : (z == 1) ? o1h : o2h));
  u16* dl = (u16*)(ws + ((z == 0) ? o0l : (z == 1) ? o1l : o2l));
  const int idx = blockIdx.x * 256 + threadIdx.x;          // 0..524287
  const int r = idx & 127, kg = (idx >> 7) & 3, kt = (idx >> 9) & 31, rt = idx >> 14;
  const float* p = src + (size_t)(rt * 128 + r) * 1024 + kt * 32 + kg * 8;
  const float4 x0 = ((const float4*)p)[0];
  const float4 x1 = ((const float4*)p)[1];
  const float xv[8] = {x0.x, x0.y, x0.z, x0.w, x1.x, x1.y, x1.z, x1.w};
  u16x8v hv, lv;
#pragma unroll
  for (int e = 0; e < 8; ++e) {
    const float x = relu ? fmaxf(xv[e], 0.f) : xv[e];
    const u16 hi = f2bf_rne(x);
    hv[e] = hi;
    lv[e] = f2bf_rne(x - bf2f(hi));
  }
  *(u16x8v*)(dh + (size_t)idx * 8) = hv;
  *(u16x8v*)(dl + (size_t)idx * 8) = lv;
}

// ---------------------------------------------------------------------------
// prep_w: W [K][N-chunk] fp32 (row stride ld, col offset c0) -> W^T split F-tiled
// one block = one (kt, ntile) -> exactly one 8KB F-tile (hi & lo).
// mode 0: 5 proj chunks (z);  mode 1: Wvo (K=2048);  mode 2: Wko (K=3072)
// ---------------------------------------------------------------------------
__global__ __launch_bounds__(256) void prep_w(
    const float* __restrict__ W0, const float* __restrict__ W1, const float* __restrict__ W2,
    char* __restrict__ ws, const int mode)
{
  __shared__ float T[32][129];
  const int kt = blockIdx.x, ntile = blockIdx.y, z = blockIdx.z;
  const float* src; int ld, c0, nkt; u16 *dh, *dl;
  if (mode == 0) {
    const int c0s[5] = {1024, 0, 2048, 0, 1024};
    src = (z == 0) ? W0 : (z <= 2) ? W1 : W2;
    ld = 3072; c0 = c0s[z]; nkt = 32;
    dh = (u16*)(ws + O_WP + (size_t)z * 4 * MiB);
    dl = (u16*)(ws + O_WP + (size_t)z * 4 * MiB + 2 * MiB);
  } else if (mode == 1) {
    src = W0; ld = 1024; c0 = 0; nkt = 64;
    dh = (u16*)(ws + O_WVO_H); dl = (u16*)(ws + O_WVO_L);
  } else {
    src = W0; ld = 1024; c0 = 0; nkt = 96;
    dh = (u16*)(ws + O_WKO_H); dl = (u16*)(ws + O_WKO_L);
  }
  const int tid = threadIdx.x;
#pragma unroll
  for (int j = 0; j < 4; ++j) {
    const int p = tid + j * 256;
    const int row = p >> 5, c4 = p & 31;
    const float4 v = *(const float4*)(src + (size_t)(kt * 32 + row) * ld + c0 + ntile * 128 + c4 * 4);
    T[row][c4 * 4 + 0] = v.x; T[row][c4 * 4 + 1] = v.y;
    T[row][c4 * 4 + 2] = v.z; T[row][c4 * 4 + 3] = v.w;
  }
  __syncthreads();
#pragma unroll
  for (int j = 0; j < 2; ++j) {
    const int c = tid + j * 256;
    const int kg = c >> 7, rr = c & 127;
    u16x8v hv, lv;
#pragma unroll
    for (int e = 0; e < 8; ++e) {
      const float x = T[kg * 8 + e][rr];
      const u16 hi = f2bf_rne(x);
      hv[e] = hi;
      lv[e] = f2bf_rne(x - bf2f(hi));
    }
    const size_t off = (size_t)(ntile * nkt + kt) * 4096 + (size_t)c * 8;
    *(u16x8v*)(dh + off) = hv;
    *(u16x8v*)(dl + off) = lv;
  }
}

// ---------------------------------------------------------------------------
// sgemm_core: C128x128 = sum over parts of A_part @ B, split-bf16 3xMFMA.
// A parts are 1024 wide (32 kt each); B has K = nkt*32 contiguous.
// Per kt: 4 waves each stage one 8KB tile (A_hi/A_lo/B_hi/B_lo) via
// global_load_lds (perfectly linear: F-tiled source). 2 barriers per kt.
// Wave quadrant: (wid>>1)*64 rows x (wid&1)*64 cols; 4x4 16x16 fragments.
// ---------------------------------------------------------------------------
__device__ __forceinline__ void sgemm_core(
    const u16* __restrict__ a0h, const u16* __restrict__ a0l,
    const u16* __restrict__ a1h, const u16* __restrict__ a1l,
    const u16* __restrict__ a2h, const u16* __restrict__ a2l,
    const u16* __restrict__ bh,  const u16* __restrict__ bl,
    const int nkt, const int mt, const int nt, f32x4 acc[4][4])
{
  __shared__ __align__(16) u16 lds[4][4096];
  const int tid = threadIdx.x;
  const int wid = tid >> 6, lane = tid & 63;
  const int lr = lane & 15, lg = lane >> 4;
  const int wm = (wid >> 1) * 64, wn = (wid & 1) * 64;
  u16* myl = &lds[wid][0];

  for (int kt = 0; kt < nkt; ++kt) {
    __syncthreads();
    const int p = kt >> 5, kk = kt & 31;
    const u16* ah = (p == 0) ? a0h : (p == 1) ? a1h : a2h;
    const u16* al = (p == 0) ? a0l : (p == 1) ? a1l : a2l;
    const u16* src;
    if      (wid == 0) src = ah + (size_t)(mt * 32 + kk) * 4096;
    else if (wid == 1) src = al + (size_t)(mt * 32 + kk) * 4096;
    else if (wid == 2) src = bh + (size_t)(nt * nkt + kt) * 4096;
    else               src = bl + (size_t)(nt * nkt + kt) * 4096;
    const u16* s = src + lane * 8;
#pragma unroll
    for (int i = 0; i < 8; ++i)
      gload16(s + i * 512, myl + i * 512);
    __syncthreads();

    bf16x8 afh[4], afl[4], bfh[4], bfl[4];
#pragma unroll
    for (int i = 0; i < 4; ++i) {
      const int ra = wm + i * 16 + lr;
      const int rb = wn + i * 16 + lr;
      afh[i] = *(const bf16x8*)&lds[0][(lg * 128 + ra) * 8];
      afl[i] = *(const bf16x8*)&lds[1][(lg * 128 + ra) * 8];
      bfh[i] = *(const bf16x8*)&lds[2][(lg * 128 + rb) * 8];
      bfl[i] = *(const bf16x8*)&lds[3][(lg * 128 + rb) * 8];
    }
#pragma unroll
    for (int i = 0; i < 4; ++i)
#pragma unroll
      for (int j = 0; j < 4; ++j) {
        acc[i][j] = __builtin_amdgcn_mfma_f32_16x16x32_bf16(afh[i], bfh[j], acc[i][j], 0, 0, 0);
        acc[i][j] = __builtin_amdgcn_mfma_f32_16x16x32_bf16(afh[i], bfl[j], acc[i][j], 0, 0, 0);
        acc[i][j] = __builtin_amdgcn_mfma_f32_16x16x32_bf16(afl[i], bfh[j], acc[i][j], 0, 0, 0);
      }
  }
}

// ---------------------------------------------------------------------------
// proj_gemm: 5 chunks; out = bf16((acc + bias) * rowmask), row-major [4096][1024]
// ---------------------------------------------------------------------------
__global__ __launch_bounds__(256) void proj_gemm(
    char* __restrict__ ws,
    const float* __restrict__ bv, const float* __restrict__ bq, const float* __restrict__ bk,
    const int* __restrict__ vm, const int* __restrict__ qm, const int* __restrict__ km)
{
  const int z = blockIdx.z, nt = blockIdx.x, mt = blockIdx.y;
  const u16* ah = (const u16*)(ws + ((z == 0) ? O_VR_H : (z <= 2) ? O_QR_H : O_KR_H));
  const u16* al = (const u16*)(ws + ((z == 0) ? O_VR_L : (z <= 2) ? O_QR_L : O_KR_L));
  const u16* bh = (const u16*)(ws + O_WP + (size_t)z * 4 * MiB);
  const u16* bl = (const u16*)(ws + O_WP + (size_t)z * 4 * MiB + 2 * MiB);
  const float* bias = (z == 0) ? bv + 1024 : (z == 1) ? bq : (z == 2) ? bq + 2048
                    : (z == 3) ? bk : bk + 1024;
  const int* msk = (z == 0) ? vm : (z <= 2) ? qm : km;
  u16* out = (u16*)(ws + O_PO + (size_t)z * 8 * MiB);

  f32x4 acc[4][4];
#pragma unroll
  for (int i = 0; i < 4; ++i)
#pragma unroll
    for (int j = 0; j < 4; ++j) {
      f32x4 zer = {0.f, 0.f, 0.f, 0.f};
      acc[i][j] = zer;
    }
  sgemm_core(ah, al, ah, al, ah, al, bh, bl, 32, mt, nt, acc);

  const int tid = threadIdx.x, wid = tid >> 6, lane = tid & 63;
  const int lr = lane & 15, lg = lane >> 4;
  const int row0 = mt * 128 + (wid >> 1) * 64;
  const int col0 = nt * 128 + (wid & 1) * 64;
#pragma unroll
  for (int i = 0; i < 4; ++i)
#pragma unroll
    for (int r = 0; r < 4; ++r) {
      const int row = row0 + i * 16 + lg * 4 + r;
      const float mf = (float)msk[row];
#pragma unroll
      for (int j = 0; j < 4; ++j) {
        const int col = col0 + j * 16 + lr;
        out[(size_t)row * 1024 + col] = f2bf_rne((acc[i][j][r] + bias[col]) * mf);
      }
    }
}

// ---------------------------------------------------------------------------
// transpose_vt: bf16 row-major [4096][1024] -> per-(b,h) transposed [64d][512key]
// z=0: q_v -> VT0 ; z=1: k_q -> VT1
// ---------------------------------------------------------------------------
__global__ __launch_bounds__(256) void transpose_vt(char* __restrict__ ws) {
  const int z = blockIdx.z, bh = blockIdx.y, kb = blockIdx.x;
  const u16* src = (const u16*)(ws + O_PO + (size_t)((z == 0) ? 2 : 4) * 8 * MiB);
  u16* dst = (u16*)(ws + ((z == 0) ? O_VT0 : O_VT1));
  __shared__ __align__(16) u16 T[64][80];
  const int tid = threadIdx.x;
  const int b = bh >> 4, h = bh & 15;
#pragma unroll
  for (int j = 0; j < 2; ++j) {
    const int p = tid + j * 256;
    const int row = p >> 3, sl = p & 7;   // row = key-in-tile, sl = 8-u16 slot of d
    const u16x8v val = *(const u16x8v*)(src + (size_t)(b * 512 + kb * 64 + row) * 1024 + h * 64 + sl * 8);
    *(u16x8v*)&T[row][sl * 8] = val;
  }
  __syncthreads();
#pragma unroll
  for (int j = 0; j < 2; ++j) {
    const int p = tid + j * 256;
    const int d = p >> 3, ks = p & 7;
    u16x8v val;
#pragma unroll
    for (int e = 0; e < 8; ++e) val[e] = T[ks * 8 + e][d];
    *(u16x8v*)(dst + (size_t)(bh * 64 + d) * 512 + kb * 64 + ks * 8) = val;
  }
}

// ---------------------------------------------------------------------------
// attn_kernel: flash attention, bf16 MFMA. grid (8 qt, 16 h, 16 = b*2+att).
// 4 waves; wave w owns q-rows [w*16, w*16+16). Tiles 64x64 bf16 in LDS with
// XOR swizzle (slot ^= row&7) written via pre-swizzled global_load_lds source.
// Output written directly as split-bf16 F-tiled (out-GEMM A operand).
// ---------------------------------------------------------------------------
__global__ __launch_bounds__(256) void attn_kernel(
    char* __restrict__ ws, const int* __restrict__ qm, const int* __restrict__ km)
{
  __shared__ __align__(16) u16 Qs[4096], Ks[4096], Vs[4096];
  __shared__ __align__(16) float Ps[4][16 * 68];
  __shared__ int msk[64];
  const int z = blockIdx.z, b = z >> 1, att = z & 1;
  const int h = blockIdx.y, q0 = blockIdx.x * 64;
  const u16 *Qg, *Kg, *VTg; const int* mg; u16 *Ohp, *Olp;
  if (att == 0) {
    Qg  = (const u16*)(ws + O_PO + 0 * 8 * MiB);   // v_q
    Kg  = (const u16*)(ws + O_PO + 1 * 8 * MiB);   // q_k
    VTg = (const u16*)(ws + O_VT0);                // q_v^T
    mg = qm; Ohp = (u16*)(ws + O_OVQ_H); Olp = (u16*)(ws + O_OVQ_L);
  } else {
    Qg  = (const u16*)(ws + O_PO + 4 * 8 * MiB);   // k_q
    Kg  = (const u16*)(ws + O_PO + 3 * 8 * MiB);   // k_k
    VTg = (const u16*)(ws + O_VT1);                // k_q^T
    mg = km; Ohp = (u16*)(ws + O_OVK_H); Olp = (u16*)(ws + O_OVK_L);
  }
  const int tid = threadIdx.x, wid = tid >> 6, lane = tid & 63;
  const int lr = lane & 15, lg = lane >> 4;

  // stage Q once (swizzled)
#pragma unroll
  for (int i = 0; i < 2; ++i) {
    const int p = wid * 128 + i * 64 + lane;
    const int row = p >> 3, sl = p & 7;
    const u16* src = Qg + (size_t)(b * 512 + q0 + row) * 1024 + h * 64 + ((sl ^ (row & 7)) * 8);
    gload16(src, &Qs[(wid * 128 + i * 64) * 8]);
  }
  __syncthreads();
  const int qrow = wid * 16 + lr;
  const bf16x8 qa0 = *(const bf16x8*)&Qs[(qrow * 8 + ((0 + lg) ^ (qrow & 7))) * 8];
  const bf16x8 qa1 = *(const bf16x8*)&Qs[(qrow * 8 + ((4 + lg) ^ (qrow & 7))) * 8];

  f32x4 oacc[4];
  float mreg[4], lreg[4];
#pragma unroll
  for (int i = 0; i < 4; ++i) {
    f32x4 zer = {0.f, 0.f, 0.f, 0.f};
    oacc[i] = zer; mreg[i] = -3.0e38f; lreg[i] = 0.f;
  }

  for (int kt = 0; kt < 8; ++kt) {
    __syncthreads();
#pragma unroll
    for (int i = 0; i < 2; ++i) {
      const int p = wid * 128 + i * 64 + lane;
      const int row = p >> 3, sl = p & 7;
      const u16* ksrc = Kg + (size_t)(b * 512 + kt * 64 + row) * 1024 + h * 64 + ((sl ^ (row & 7)) * 8);
      gload16(ksrc, &Ks[(wid * 128 + i * 64) * 8]);
      const u16* vsrc = VTg + (size_t)((b * 16 + h) * 64 + row) * 512 + kt * 64 + ((sl ^ (row & 7)) * 8);
      gload16(vsrc, &Vs[(wid * 128 + i * 64) * 8]);
    }
    if (tid < 64) msk[tid] = mg[b * 512 + kt * 64 + tid];
    __syncthreads();

    // S = Q K^T   (C: row q = lg*4+r, col key = nt*16+lr)
    f32x4 s[4];
#pragma unroll
    for (int nt = 0; nt < 4; ++nt) {
      f32x4 zer = {0.f, 0.f, 0.f, 0.f};
      s[nt] = zer;
      const int kr = nt * 16 + lr;
      const bf16x8 kb0 = *(const bf16x8*)&Ks[(kr * 8 + ((0 + lg) ^ (kr & 7))) * 8];
      const bf16x8 kb1 = *(const bf16x8*)&Ks[(kr * 8 + ((4 + lg) ^ (kr & 7))) * 8];
      s[nt] = __builtin_amdgcn_mfma_f32_16x16x32_bf16(qa0, kb0, s[nt], 0, 0, 0);
      s[nt] = __builtin_amdgcn_mfma_f32_16x16x32_bf16(qa1, kb1, s[nt], 0, 0, 0);
    }
    // mask (before scale, per reference) then scale
#pragma unroll
    for (int nt = 0; nt < 4; ++nt) {
      const int mk = msk[nt * 16 + lr];
#pragma unroll
      for (int r = 0; r < 4; ++r)
        s[nt][r] = mk ? s[nt][r] * ATT_SCALE : NEGS;
    }
    // online softmax per q-row
#pragma unroll
    for (int r = 0; r < 4; ++r) {
      float mx = fmaxf(fmaxf(s[0][r], s[1][r]), fmaxf(s[2][r], s[3][r]));
      mx = fmaxf(mx, __shfl_xor(mx, 1)); mx = fmaxf(mx, __shfl_xor(mx, 2));
      mx = fmaxf(mx, __shfl_xor(mx, 4)); mx = fmaxf(mx, __shfl_xor(mx, 8));
      const float nm = fmaxf(mreg[r], mx);
      const float corr = __expf(mreg[r] - nm);
      float ps = 0.f;
#pragma unroll
      for (int nt = 0; nt < 4; ++nt) {
        const float pv = __expf(s[nt][r] - nm);
        s[nt][r] = pv; ps += pv;
      }
      ps += __shfl_xor(ps, 1); ps += __shfl_xor(ps, 2);
      ps += __shfl_xor(ps, 4); ps += __shfl_xor(ps, 8);
      lreg[r] = lreg[r] * corr + ps;
      mreg[r] = nm;
#pragma unroll
      for (int d = 0; d < 4; ++d) oacc[d][r] *= corr;
    }
    // P -> wave-private LDS [16 q][68 key] (f32), then PV
    float* Pw = &Ps[wid][0];
#pragma unroll
    for (int nt = 0; nt < 4; ++nt)
#pragma unroll
      for (int r = 0; r < 4; ++r)
        Pw[(lg * 4 + r) * 68 + nt * 16 + lr] = s[nt][r];
#pragma unroll
    for (int ks = 0; ks < 2; ++ks) {
      const float* pp = &Pw[lr * 68 + ks * 32 + lg * 8];
      const f32x4 p0 = *(const f32x4*)pp;
      const f32x4 p1 = *(const f32x4*)(pp + 4);
      bf16x8 pa;
      pa[0] = (short)f2bf_rne(p0[0]); pa[1] = (short)f2bf_rne(p0[1]);
      pa[2] = (short)f2bf_rne(p0[2]); pa[3] = (short)f2bf_rne(p0[3]);
      pa[4] = (short)f2bf_rne(p1[0]); pa[5] = (short)f2bf_rne(p1[1]);
      pa[6] = (short)f2bf_rne(p1[2]); pa[7] = (short)f2bf_rne(p1[3]);
#pragma unroll
      for (int d = 0; d < 4; ++d) {
        const int vr = d * 16 + lr;
        const bf16x8 vb = *(const bf16x8*)&Vs[(vr * 8 + ((ks * 4 + lg) ^ (vr & 7))) * 8];
        oacc[d] = __builtin_amdgcn_mfma_f32_16x16x32_bf16(pa, vb, oacc[d], 0, 0, 0);
      }
    }
  }

  // epilogue: O/l, split to hi/lo, store in F-tiled layout (out-GEMM operand)
#pragma unroll
  for (int r = 0; r < 4; ++r) {
    const float inv = 1.0f / lreg[r];
    const int row = b * 512 + q0 + wid * 16 + lg * 4 + r;
    const int rt = row >> 7, rr = row & 127;
#pragma unroll
    for (int d = 0; d < 4; ++d) {
      const int col = h * 64 + d * 16 + lr;
      const int ktc = col >> 5, kg = (col >> 3) & 3, e = col & 7;
      const size_t off = ((((size_t)rt * 32 + ktc) * 4 + kg) * 128 + rr) * 8 + e;
      const float x = oacc[d][r] * inv;
      const u16 hi = f2bf_rne(x);
      Ohp[off] = hi;
      Olp[off] = f2bf_rne(x - bf2f(hi));
    }
  }
}

// ---------------------------------------------------------------------------
// out_gemm: z=0: [v|vq]@Wvo+bvo -> d_out+4M ; z=1: [v|vq|vk]@Wko+bko -> d_out
// ---------------------------------------------------------------------------
__global__ __launch_bounds__(256) void out_gemm(
    char* __restrict__ ws, const float* __restrict__ bvo, const float* __restrict__ bko,
    float* __restrict__ dout)
{
  const int z = blockIdx.z, nt = blockIdx.x, mt = blockIdx.y;
  const u16* a0h = (const u16*)(ws + O_V2_H);
  const u16* a0l = (const u16*)(ws + O_V2_L);
  const u16* a1h = (const u16*)(ws + O_OVQ_H);
  const u16* a1l = (const u16*)(ws + O_OVQ_L);
  const u16* a2h = (const u16*)(ws + O_OVK_H);
  const u16* a2l = (const u16*)(ws + O_OVK_L);
  const int nkt = z ? 96 : 64;
  const u16* bh = (const u16*)(ws + (z ? O_WKO_H : O_WVO_H));
  const u16* bl = (const u16*)(ws + (z ? O_WKO_L : O_WVO_L));
  const float* bias = z ? bko : bvo;
  float* dst = z ? dout : (dout + (size_t)4096 * 1024);

  f32x4 acc[4][4];
#pragma unroll
  for (int i = 0; i < 4; ++i)
#pragma unroll
    for (int j = 0; j < 4; ++j) {
      f32x4 zer = {0.f, 0.f, 0.f, 0.f};
      acc[i][j] = zer;
    }
  sgemm_core(a0h, a0l, a1h, a1l, a2h, a2l, bh, bl, nkt, mt, nt, acc);

  const int tid = threadIdx.x, wid = tid >> 6, lane = tid & 63;
  const int lr = lane & 15, lg = lane >> 4;
  const int row0 = mt * 128 + (wid >> 1) * 64;
  const int col0 = nt * 128 + (wid & 1) * 64;
#pragma unroll
  for (int i = 0; i < 4; ++i)
#pragma unroll
    for (int r = 0; r < 4; ++r) {
      const int row = row0 + i * 16 + lg * 4 + r;
#pragma unroll
      for (int j = 0; j < 4; ++j) {
        const int col = col0 + j * 16 + lr;
        dst[(size_t)row * 1024 + col] = acc[i][j][r] + bias[col];
      }
    }
}

// ---------------------------------------------------------------------------
extern "C" void kernel_launch(void* const* d_in, const int* in_sizes, int n_in,
                              void* d_out, int out_size, void* d_ws, size_t ws_size,
                              hipStream_t stream) {
  const float* v  = (const float*)d_in[0];
  const float* q  = (const float*)d_in[1];
  const float* k  = (const float*)d_in[2];
  const int* vm   = (const int*)d_in[3];
  const int* qm   = (const int*)d_in[4];
  const int* km   = (const int*)d_in[5];
  const float* Wv = (const float*)d_in[6];
  const float* bv = (const float*)d_in[7];
  const float* Wq = (const float*)d_in[8];
  const float* bq = (const float*)d_in[9];
  const float* Wk = (const float*)d_in[10];
  const float* bk = (const float*)d_in[11];
  const float* Wvo = (const float*)d_in[12];
  const float* bvo = (const float*)d_in[13];
  const float* Wko = (const float*)d_in[14];
  const float* bko = (const float*)d_in[15];
  char* ws = (char*)d_ws;
  float* out = (float*)d_out;

  // Phase A: split/tiling converts for projections
  prep_act<<<dim3(2048, 1, 3), 256, 0, stream>>>(v, q, k, ws, 1,
      O_VR_H, O_VR_L, O_QR_H, O_QR_L, O_KR_H, O_KR_L);
  prep_w<<<dim3(32, 8, 5), 256, 0, stream>>>(Wv, Wq, Wk, ws, 0);
  // Phase B: 5 projection GEMMs (relu'd/split A, split W^T) -> bf16 row-major
  proj_gemm<<<dim3(8, 32, 5), 256, 0, stream>>>(ws, bv, bq, bk, vm, qm, km);
  // Phase C: transpose value tensors for PV
  transpose_vt<<<dim3(8, 128, 2), 256, 0, stream>>>(ws);
  // Phase D: both attentions -> split-tiled O
  attn_kernel<<<dim3(8, 16, 16), 256, 0, stream>>>(ws, qm, km);
  // Phase E: split/tiling converts for output GEMMs
  prep_act<<<dim3(2048, 1, 1), 256, 0, stream>>>(v, v, v, ws, 0,
      O_V2_H, O_V2_L, O_V2_H, O_V2_L, O_V2_H, O_V2_L);
  prep_w<<<dim3(64, 8, 1), 256, 0, stream>>>(Wvo, Wvo, Wvo, ws, 1);
  prep_w<<<dim3(96, 8, 1), 256, 0, stream>>>(Wko, Wko, Wko, ws, 2);
  // Phase F: output GEMMs -> d_out = [updated_V ; updated_v]
  out_gemm<<<dim3(8, 32, 2), 256, 0, stream>>>(ws, bvo, bko, out);
}

// Round 5
// 462.137 us; speedup vs baseline: 4.1620x; 1.1134x over previous
//
#include <hip/hip_runtime.h>

// ---------------------------------------------------------------------------
// InterModalityUpdate: B=8, NO=512, O=1024, H=16, DH=64. M = 4096 rows.
// Strategy: split-bf16 (3xMFMA) emulated-fp32 GEMMs + single-bf16 MFMA attn.
// R4: XCD-aware block swizzle on all heavy kernels; proj uses 2-MFMA split
//     (hh + lo_a*hi_b) since its output is bf16-rounded anyway.
// ---------------------------------------------------------------------------

typedef float  f32x4  __attribute__((ext_vector_type(4)));
typedef short  bf16x8 __attribute__((ext_vector_type(8)));
typedef unsigned short u16;
typedef unsigned short u16x8v __attribute__((ext_vector_type(8)));

constexpr float ATT_SCALE = 0.125f;     // 1/sqrt(64)
constexpr float NEGS      = -1.25e8f;   // (-1e9) * SCALE (mask applied before scale)

#define MiB (size_t(1) << 20)
// ---- workspace layout (bytes). Peak live = 108 MiB.
constexpr size_t O_VR_H = 0*MiB,  O_VR_L = 8*MiB;    // relu-split v (F-tiled)
constexpr size_t O_QR_H = 16*MiB, O_QR_L = 24*MiB;   // relu-split q
constexpr size_t O_KR_H = 32*MiB, O_KR_L = 40*MiB;   // relu-split k
constexpr size_t O_WP   = 48*MiB;                    // 5 proj W chunks: hi@48+4z, lo@50+4z
constexpr size_t O_PO   = 68*MiB;                    // proj outs bf16 row-major: z*8MiB
                                                     // {v_q,q_k,q_v,k_k,k_q}
constexpr size_t O_VT0  = 0*MiB,  O_VT1 = 8*MiB;     // q_v^T, k_q^T  [b][h][64d][512key]
constexpr size_t O_OVQ_H= 16*MiB, O_OVQ_L= 24*MiB;   // attn out vq split (F-tiled)
constexpr size_t O_OVK_H= 32*MiB, O_OVK_L= 40*MiB;   // attn out vk split
constexpr size_t O_V2_H = 48*MiB, O_V2_L = 56*MiB;   // v (no relu) split
constexpr size_t O_WVO_H= 64*MiB, O_WVO_L= 68*MiB;   // Wvo^T split (K=2048)
constexpr size_t O_WKO_H= 72*MiB, O_WKO_L= 78*MiB;   // Wko^T split (K=3072)

// ---- helpers ---------------------------------------------------------------
__device__ __forceinline__ u16 f2bf_rne(float x) {
  unsigned u = __float_as_uint(x);
  return (u16)((u + 0x7FFFu + ((u >> 16) & 1u)) >> 16);
}
__device__ __forceinline__ float bf2f(u16 h) {
  return __uint_as_float(((unsigned)h) << 16);
}
__device__ __forceinline__ void gload16(const void* g, void* l) {
  __builtin_amdgcn_global_load_lds(
      (const __attribute__((address_space(1))) unsigned int*)g,
      (__attribute__((address_space(3))) unsigned int*)l, 16, 0, 0);
}
// bijective XCD swizzle: nwg % 8 == 0 required (holds for all our grids)
template <int NWG>
__device__ __forceinline__ int xcd_swz(int bid) {
  return (bid & 7) * (NWG >> 3) + (bid >> 3);
}

// ---------------------------------------------------------------------------
// prep_act: fp32 [4096][1024] -> split bf16 hi/lo in F-tiled layout
//   F layout: chunk idx = ((rt*32 + kt)*4 + kg)*128 + r  holds 8 consecutive k.
// ---------------------------------------------------------------------------
__global__ __launch_bounds__(256) void prep_act(
    const float* __restrict__ s0, const float* __restrict__ s1, const float* __restrict__ s2,
    char* __restrict__ ws, const int relu,
    const size_t o0h, const size_t o0l, const size_t o1h, const size_t o1l,
    const size_t o2h, const size_t o2l)
{
  const int z = blockIdx.z;
  const float* src = (z == 0) ? s0 : (z == 1) ? s1 : s2;
  u16* dh = (u16*)(ws + ((z == 0) ? o0h : (z == 1) ? o1h : o2h));
  u16* dl = (u16*)(ws + ((z == 0) ? o0l : (z == 1) ? o1l : o2l));
  const int idx = blockIdx.x * 256 + threadIdx.x;          // 0..524287
  const int r = idx & 127, kg = (idx >> 7) & 3, kt = (idx >> 9) & 31, rt = idx >> 14;
  const float* p = src + (size_t)(rt * 128 + r) * 1024 + kt * 32 + kg * 8;
  const float4 x0 = ((const float4*)p)[0];
  const float4 x1 = ((const float4*)p)[1];
  const float xv[8] = {x0.x, x0.y, x0.z, x0.w, x1.x, x1.y, x1.z, x1.w};
  u16x8v hv, lv;
#pragma unroll
  for (int e = 0; e < 8; ++e) {
    const float x = relu ? fmaxf(xv[e], 0.f) : xv[e];
    const u16 hi = f2bf_rne(x);
    hv[e] = hi;
    lv[e] = f2bf_rne(x - bf2f(hi));
  }
  *(u16x8v*)(dh + (size_t)idx * 8) = hv;
  *(u16x8v*)(dl + (size_t)idx * 8) = lv;
}

// ---------------------------------------------------------------------------
// prep_w: W [K][N-chunk] fp32 (row stride ld, col offset c0) -> W^T split F-tiled
// mode 0: 5 proj chunks (z);  mode 1: Wvo (K=2048);  mode 2: Wko (K=3072)
// ---------------------------------------------------------------------------
__global__ __launch_bounds__(256) void prep_w(
    const float* __restrict__ W0, const float* __restrict__ W1, const float* __restrict__ W2,
    char* __restrict__ ws, const int mode)
{
  __shared__ float T[32][129];
  const int kt = blockIdx.x, ntile = blockIdx.y, z = blockIdx.z;
  const float* src; int ld, c0, nkt; u16 *dh, *dl;
  if (mode == 0) {
    const int c0s[5] = {1024, 0, 2048, 0, 1024};
    src = (z == 0) ? W0 : (z <= 2) ? W1 : W2;
    ld = 3072; c0 = c0s[z]; nkt = 32;
    dh = (u16*)(ws + O_WP + (size_t)z * 4 * MiB);
    dl = (u16*)(ws + O_WP + (size_t)z * 4 * MiB + 2 * MiB);
  } else if (mode == 1) {
    src = W0; ld = 1024; c0 = 0; nkt = 64;
    dh = (u16*)(ws + O_WVO_H); dl = (u16*)(ws + O_WVO_L);
  } else {
    src = W0; ld = 1024; c0 = 0; nkt = 96;
    dh = (u16*)(ws + O_WKO_H); dl = (u16*)(ws + O_WKO_L);
  }
  const int tid = threadIdx.x;
#pragma unroll
  for (int j = 0; j < 4; ++j) {
    const int p = tid + j * 256;
    const int row = p >> 5, c4 = p & 31;
    const float4 v = *(const float4*)(src + (size_t)(kt * 32 + row) * ld + c0 + ntile * 128 + c4 * 4);
    T[row][c4 * 4 + 0] = v.x; T[row][c4 * 4 + 1] = v.y;
    T[row][c4 * 4 + 2] = v.z; T[row][c4 * 4 + 3] = v.w;
  }
  __syncthreads();
#pragma unroll
  for (int j = 0; j < 2; ++j) {
    const int c = tid + j * 256;
    const int kg = c >> 7, rr = c & 127;
    u16x8v hv, lv;
#pragma unroll
    for (int e = 0; e < 8; ++e) {
      const float x = T[kg * 8 + e][rr];
      const u16 hi = f2bf_rne(x);
      hv[e] = hi;
      lv[e] = f2bf_rne(x - bf2f(hi));
    }
    const size_t off = (size_t)(ntile * nkt + kt) * 4096 + (size_t)c * 8;
    *(u16x8v*)(dh + off) = hv;
    *(u16x8v*)(dl + off) = lv;
  }
}

// ---------------------------------------------------------------------------
// sgemm_core<NM>: C128x128 = sum over parts of A_part @ B, split-bf16.
// NM=3: hh + hl + lh (full split, for out_gemm).
// NM=2: hh + lh only (B-lo never staged; proj output is bf16-rounded anyway).
// Per kt: waves stage 8KB tiles (A_hi/A_lo/B_hi[/B_lo]) via global_load_lds
// (linear dest, F-tiled source). 2 barriers per kt.
// ---------------------------------------------------------------------------
template <int NM>
__device__ __forceinline__ void sgemm_core(
    const u16* __restrict__ a0h, const u16* __restrict__ a0l,
    const u16* __restrict__ a1h, const u16* __restrict__ a1l,
    const u16* __restrict__ a2h, const u16* __restrict__ a2l,
    const u16* __restrict__ bh,  const u16* __restrict__ bl,
    const int nkt, const int mt, const int nt, f32x4 acc[4][4])
{
  __shared__ __align__(16) u16 lds[4][4096];
  const int tid = threadIdx.x;
  const int wid = tid >> 6, lane = tid & 63;
  const int lr = lane & 15, lg = lane >> 4;
  const int wm = (wid >> 1) * 64, wn = (wid & 1) * 64;
  u16* myl = &lds[wid][0];

  for (int kt = 0; kt < nkt; ++kt) {
    __syncthreads();
    const int p = kt >> 5, kk = kt & 31;
    const u16* ah = (p == 0) ? a0h : (p == 1) ? a1h : a2h;
    const u16* al = (p == 0) ? a0l : (p == 1) ? a1l : a2l;
    const u16* src = nullptr;
    if      (wid == 0) src = ah + (size_t)(mt * 32 + kk) * 4096;
    else if (wid == 1) src = al + (size_t)(mt * 32 + kk) * 4096;
    else if (wid == 2) src = bh + (size_t)(nt * nkt + kt) * 4096;
    else if (NM == 3)  src = bl + (size_t)(nt * nkt + kt) * 4096;
    if (src) {
      const u16* s = src + lane * 8;
#pragma unroll
      for (int i = 0; i < 8; ++i)
        gload16(s + i * 512, myl + i * 512);
    }
    __syncthreads();

    bf16x8 afh[4], afl[4], bfh[4], bfl[4];
#pragma unroll
    for (int i = 0; i < 4; ++i) {
      const int ra = wm + i * 16 + lr;
      const int rb = wn + i * 16 + lr;
      afh[i] = *(const bf16x8*)&lds[0][(lg * 128 + ra) * 8];
      afl[i] = *(const bf16x8*)&lds[1][(lg * 128 + ra) * 8];
      bfh[i] = *(const bf16x8*)&lds[2][(lg * 128 + rb) * 8];
      if (NM == 3) bfl[i] = *(const bf16x8*)&lds[3][(lg * 128 + rb) * 8];
    }
#pragma unroll
    for (int i = 0; i < 4; ++i)
#pragma unroll
      for (int j = 0; j < 4; ++j) {
        acc[i][j] = __builtin_amdgcn_mfma_f32_16x16x32_bf16(afh[i], bfh[j], acc[i][j], 0, 0, 0);
        if (NM == 3)
          acc[i][j] = __builtin_amdgcn_mfma_f32_16x16x32_bf16(afh[i], bfl[j], acc[i][j], 0, 0, 0);
        acc[i][j] = __builtin_amdgcn_mfma_f32_16x16x32_bf16(afl[i], bfh[j], acc[i][j], 0, 0, 0);
      }
  }
}

// ---------------------------------------------------------------------------
// proj_gemm: 5 chunks; out = bf16((acc + bias) * rowmask), row-major [4096][1024]
// 1-D grid 1280, XCD-swizzled; swz decomposed nt-fastest so the 8 blocks
// sharing an A-panel are contiguous (same XCD L2).
// ---------------------------------------------------------------------------
__global__ __launch_bounds__(256) void proj_gemm(
    char* __restrict__ ws,
    const float* __restrict__ bv, const float* __restrict__ bq, const float* __restrict__ bk,
    const int* __restrict__ vm, const int* __restrict__ qm, const int* __restrict__ km)
{
  const int swz = xcd_swz<1280>(blockIdx.x);
  const int nt = swz & 7, t = swz >> 3;
  const int mt = t & 31, z = t >> 5;

  const u16* ah = (const u16*)(ws + ((z == 0) ? O_VR_H : (z <= 2) ? O_QR_H : O_KR_H));
  const u16* al = (const u16*)(ws + ((z == 0) ? O_VR_L : (z <= 2) ? O_QR_L : O_KR_L));
  const u16* bh = (const u16*)(ws + O_WP + (size_t)z * 4 * MiB);
  const float* bias = (z == 0) ? bv + 1024 : (z == 1) ? bq : (z == 2) ? bq + 2048
                    : (z == 3) ? bk : bk + 1024;
  const int* msk = (z == 0) ? vm : (z <= 2) ? qm : km;
  u16* out = (u16*)(ws + O_PO + (size_t)z * 8 * MiB);

  f32x4 acc[4][4];
#pragma unroll
  for (int i = 0; i < 4; ++i)
#pragma unroll
    for (int j = 0; j < 4; ++j) {
      f32x4 zer = {0.f, 0.f, 0.f, 0.f};
      acc[i][j] = zer;
    }
  sgemm_core<2>(ah, al, ah, al, ah, al, bh, nullptr, 32, mt, nt, acc);

  const int tid = threadIdx.x, wid = tid >> 6, lane = tid & 63;
  const int lr = lane & 15, lg = lane >> 4;
  const int row0 = mt * 128 + (wid >> 1) * 64;
  const int col0 = nt * 128 + (wid & 1) * 64;
#pragma unroll
  for (int i = 0; i < 4; ++i)
#pragma unroll
    for (int r = 0; r < 4; ++r) {
      const int row = row0 + i * 16 + lg * 4 + r;
      const float mf = (float)msk[row];
#pragma unroll
      for (int j = 0; j < 4; ++j) {
        const int col = col0 + j * 16 + lr;
        out[(size_t)row * 1024 + col] = f2bf_rne((acc[i][j][r] + bias[col]) * mf);
      }
    }
}

// ---------------------------------------------------------------------------
// transpose_vt: bf16 row-major [4096][1024] -> per-(b,h) transposed [64d][512key]
// z=0: q_v -> VT0 ; z=1: k_q -> VT1
// ---------------------------------------------------------------------------
__global__ __launch_bounds__(256) void transpose_vt(char* __restrict__ ws) {
  const int z = blockIdx.z, bh = blockIdx.y, kb = blockIdx.x;
  const u16* src = (const u16*)(ws + O_PO + (size_t)((z == 0) ? 2 : 4) * 8 * MiB);
  u16* dst = (u16*)(ws + ((z == 0) ? O_VT0 : O_VT1));
  __shared__ __align__(16) u16 T[64][80];
  const int tid = threadIdx.x;
  const int b = bh >> 4, h = bh & 15;
#pragma unroll
  for (int j = 0; j < 2; ++j) {
    const int p = tid + j * 256;
    const int row = p >> 3, sl = p & 7;   // row = key-in-tile, sl = 8-u16 slot of d
    const u16x8v val = *(const u16x8v*)(src + (size_t)(b * 512 + kb * 64 + row) * 1024 + h * 64 + sl * 8);
    *(u16x8v*)&T[row][sl * 8] = val;
  }
  __syncthreads();
#pragma unroll
  for (int j = 0; j < 2; ++j) {
    const int p = tid + j * 256;
    const int d = p >> 3, ks = p & 7;
    u16x8v val;
#pragma unroll
    for (int e = 0; e < 8; ++e) val[e] = T[ks * 8 + e][d];
    *(u16x8v*)(dst + (size_t)(bh * 64 + d) * 512 + kb * 64 + ks * 8) = val;
  }
}

// ---------------------------------------------------------------------------
// attn_kernel: flash attention, bf16 MFMA. 1-D grid 2048, XCD-swizzled so the
// 8 q-tiles sharing one (b,att,h)'s K/V are XCD-contiguous.
// 4 waves; wave w owns q-rows [w*16, w*16+16). Tiles 64x64 bf16 in LDS with
// XOR swizzle (slot ^= row&7) via pre-swizzled global_load_lds source.
// Output written directly as split-bf16 F-tiled (out-GEMM A operand).
// ---------------------------------------------------------------------------
__global__ __launch_bounds__(256) void attn_kernel(
    char* __restrict__ ws, const int* __restrict__ qm, const int* __restrict__ km)
{
  __shared__ __align__(16) u16 Qs[4096], Ks[4096], Vs[4096];
  __shared__ __align__(16) float Ps[4][16 * 68];
  __shared__ int msk[64];
  const int swz = xcd_swz<2048>(blockIdx.x);
  const int qt = swz & 7, h = (swz >> 3) & 15, zz = swz >> 7;
  const int b = zz >> 1, att = zz & 1;
  const int q0 = qt * 64;
  const u16 *Qg, *Kg, *VTg; const int* mg; u16 *Ohp, *Olp;
  if (att == 0) {
    Qg  = (const u16*)(ws + O_PO + 0 * 8 * MiB);   // v_q
    Kg  = (const u16*)(ws + O_PO + 1 * 8 * MiB);   // q_k
    VTg = (const u16*)(ws + O_VT0);                // q_v^T
    mg = qm; Ohp = (u16*)(ws + O_OVQ_H); Olp = (u16*)(ws + O_OVQ_L);
  } else {
    Qg  = (const u16*)(ws + O_PO + 4 * 8 * MiB);   // k_q
    Kg  = (const u16*)(ws + O_PO + 3 * 8 * MiB);   // k_k
    VTg = (const u16*)(ws + O_VT1);                // k_q^T
    mg = km; Ohp = (u16*)(ws + O_OVK_H); Olp = (u16*)(ws + O_OVK_L);
  }
  const int tid = threadIdx.x, wid = tid >> 6, lane = tid & 63;
  const int lr = lane & 15, lg = lane >> 4;

  // stage Q once (swizzled)
#pragma unroll
  for (int i = 0; i < 2; ++i) {
    const int p = wid * 128 + i * 64 + lane;
    const int row = p >> 3, sl = p & 7;
    const u16* src = Qg + (size_t)(b * 512 + q0 + row) * 1024 + h * 64 + ((sl ^ (row & 7)) * 8);
    gload16(src, &Qs[(wid * 128 + i * 64) * 8]);
  }
  __syncthreads();
  const int qrow = wid * 16 + lr;
  const bf16x8 qa0 = *(const bf16x8*)&Qs[(qrow * 8 + ((0 + lg) ^ (qrow & 7))) * 8];
  const bf16x8 qa1 = *(const bf16x8*)&Qs[(qrow * 8 + ((4 + lg) ^ (qrow & 7))) * 8];

  f32x4 oacc[4];
  float mreg[4], lreg[4];
#pragma unroll
  for (int i = 0; i < 4; ++i) {
    f32x4 zer = {0.f, 0.f, 0.f, 0.f};
    oacc[i] = zer; mreg[i] = -3.0e38f; lreg[i] = 0.f;
  }

  for (int kt = 0; kt < 8; ++kt) {
    __syncthreads();
#pragma unroll
    for (int i = 0; i < 2; ++i) {
      const int p = wid * 128 + i * 64 + lane;
      const int row = p >> 3, sl = p & 7;
      const u16* ksrc = Kg + (size_t)(b * 512 + kt * 64 + row) * 1024 + h * 64 + ((sl ^ (row & 7)) * 8);
      gload16(ksrc, &Ks[(wid * 128 + i * 64) * 8]);
      const u16* vsrc = VTg + (size_t)((b * 16 + h) * 64 + row) * 512 + kt * 64 + ((sl ^ (row & 7)) * 8);
      gload16(vsrc, &Vs[(wid * 128 + i * 64) * 8]);
    }
    if (tid < 64) msk[tid] = mg[b * 512 + kt * 64 + tid];
    __syncthreads();

    // S = Q K^T   (C: row q = lg*4+r, col key = nt*16+lr)
    f32x4 s[4];
#pragma unroll
    for (int nt = 0; nt < 4; ++nt) {
      f32x4 zer = {0.f, 0.f, 0.f, 0.f};
      s[nt] = zer;
      const int kr = nt * 16 + lr;
      const bf16x8 kb0 = *(const bf16x8*)&Ks[(kr * 8 + ((0 + lg) ^ (kr & 7))) * 8];
      const bf16x8 kb1 = *(const bf16x8*)&Ks[(kr * 8 + ((4 + lg) ^ (kr & 7))) * 8];
      s[nt] = __builtin_amdgcn_mfma_f32_16x16x32_bf16(qa0, kb0, s[nt], 0, 0, 0);
      s[nt] = __builtin_amdgcn_mfma_f32_16x16x32_bf16(qa1, kb1, s[nt], 0, 0, 0);
    }
    // mask (before scale, per reference) then scale
#pragma unroll
    for (int nt = 0; nt < 4; ++nt) {
      const int mk = msk[nt * 16 + lr];
#pragma unroll
      for (int r = 0; r < 4; ++r)
        s[nt][r] = mk ? s[nt][r] * ATT_SCALE : NEGS;
    }
    // online softmax per q-row
#pragma unroll
    for (int r = 0; r < 4; ++r) {
      float mx = fmaxf(fmaxf(s[0][r], s[1][r]), fmaxf(s[2][r], s[3][r]));
      mx = fmaxf(mx, __shfl_xor(mx, 1)); mx = fmaxf(mx, __shfl_xor(mx, 2));
      mx = fmaxf(mx, __shfl_xor(mx, 4)); mx = fmaxf(mx, __shfl_xor(mx, 8));
      const float nm = fmaxf(mreg[r], mx);
      const float corr = __expf(mreg[r] - nm);
      float ps = 0.f;
#pragma unroll
      for (int nt = 0; nt < 4; ++nt) {
        const float pv = __expf(s[nt][r] - nm);
        s[nt][r] = pv; ps += pv;
      }
      ps += __shfl_xor(ps, 1); ps += __shfl_xor(ps, 2);
      ps += __shfl_xor(ps, 4); ps += __shfl_xor(ps, 8);
      lreg[r] = lreg[r] * corr + ps;
      mreg[r] = nm;
#pragma unroll
      for (int d = 0; d < 4; ++d) oacc[d][r] *= corr;
    }
    // P -> wave-private LDS [16 q][68 key] (f32), then PV
    float* Pw = &Ps[wid][0];
#pragma unroll
    for (int nt = 0; nt < 4; ++nt)
#pragma unroll
      for (int r = 0; r < 4; ++r)
        Pw[(lg * 4 + r) * 68 + nt * 16 + lr] = s[nt][r];
#pragma unroll
    for (int ks = 0; ks < 2; ++ks) {
      const float* pp = &Pw[lr * 68 + ks * 32 + lg * 8];
      const f32x4 p0 = *(const f32x4*)pp;
      const f32x4 p1 = *(const f32x4*)(pp + 4);
      bf16x8 pa;
      pa[0] = (short)f2bf_rne(p0[0]); pa[1] = (short)f2bf_rne(p0[1]);
      pa[2] = (short)f2bf_rne(p0[2]); pa[3] = (short)f2bf_rne(p0[3]);
      pa[4] = (short)f2bf_rne(p1[0]); pa[5] = (short)f2bf_rne(p1[1]);
      pa[6] = (short)f2bf_rne(p1[2]); pa[7] = (short)f2bf_rne(p1[3]);
#pragma unroll
      for (int d = 0; d < 4; ++d) {
        const int vr = d * 16 + lr;
        const bf16x8 vb = *(const bf16x8*)&Vs[(vr * 8 + ((ks * 4 + lg) ^ (vr & 7))) * 8];
        oacc[d] = __builtin_amdgcn_mfma_f32_16x16x32_bf16(pa, vb, oacc[d], 0, 0, 0);
      }
    }
  }

  // epilogue: O/l, split to hi/lo, store in F-tiled layout (out-GEMM operand)
#pragma unroll
  for (int r = 0; r < 4; ++r) {
    const float inv = 1.0f / lreg[r];
    const int row = b * 512 + q0 + wid * 16 + lg * 4 + r;
    const int rt = row >> 7, rr = row & 127;
#pragma unroll
    for (int d = 0; d < 4; ++d) {
      const int col = h * 64 + d * 16 + lr;
      const int ktc = col >> 5, kg = (col >> 3) & 3, e = col & 7;
      const size_t off = ((((size_t)rt * 32 + ktc) * 4 + kg) * 128 + rr) * 8 + e;
      const float x = oacc[d][r] * inv;
      const u16 hi = f2bf_rne(x);
      Ohp[off] = hi;
      Olp[off] = f2bf_rne(x - bf2f(hi));
    }
  }
}

// ---------------------------------------------------------------------------
// out_gemm: z=0: [v|vq]@Wvo+bvo -> d_out+4M ; z=1: [v|vq|vk]@Wko+bko -> d_out
// 1-D grid 512, XCD-swizzled; decomposition (nt,z,mt) so both z share an
// XCD range (balances K=2048 vs K=3072 work) and A panels are reused by
// 16 in-XCD blocks (2z x 8nt).
// ---------------------------------------------------------------------------
__global__ __launch_bounds__(256) void out_gemm(
    char* __restrict__ ws, const float* __restrict__ bvo, const float* __restrict__ bko,
    float* __restrict__ dout)
{
  const int swz = xcd_swz<512>(blockIdx.x);
  const int nt = swz & 7, z = (swz >> 3) & 1, mt = swz >> 4;

  const u16* a0h = (const u16*)(ws + O_V2_H);
  const u16* a0l = (const u16*)(ws + O_V2_L);
  const u16* a1h = (const u16*)(ws + O_OVQ_H);
  const u16* a1l = (const u16*)(ws + O_OVQ_L);
  const u16* a2h = (const u16*)(ws + O_OVK_H);
  const u16* a2l = (const u16*)(ws + O_OVK_L);
  const int nkt = z ? 96 : 64;
  const u16* bh = (const u16*)(ws + (z ? O_WKO_H : O_WVO_H));
  const u16* bl = (const u16*)(ws + (z ? O_WKO_L : O_WVO_L));
  const float* bias = z ? bko : bvo;
  float* dst = z ? dout : (dout + (size_t)4096 * 1024);

  f32x4 acc[4][4];
#pragma unroll
  for (int i = 0; i < 4; ++i)
#pragma unroll
    for (int j = 0; j < 4; ++j) {
      f32x4 zer = {0.f, 0.f, 0.f, 0.f};
      acc[i][j] = zer;
    }
  sgemm_core<3>(a0h, a0l, a1h, a1l, a2h, a2l, bh, bl, nkt, mt, nt, acc);

  const int tid = threadIdx.x, wid = tid >> 6, lane = tid & 63;
  const int lr = lane & 15, lg = lane >> 4;
  const int row0 = mt * 128 + (wid >> 1) * 64;
  const int col0 = nt * 128 + (wid & 1) * 64;
#pragma unroll
  for (int i = 0; i < 4; ++i)
#pragma unroll
    for (int r = 0; r < 4; ++r) {
      const int row = row0 + i * 16 + lg * 4 + r;
#pragma unroll
      for (int j = 0; j < 4; ++j) {
        const int col = col0 + j * 16 + lr;
        dst[(size_t)row * 1024 + col] = acc[i][j][r] + bias[col];
      }
    }
}

// ---------------------------------------------------------------------------
extern "C" void kernel_launch(void* const* d_in, const int* in_sizes, int n_in,
                              void* d_out, int out_size, void* d_ws, size_t ws_size,
                              hipStream_t stream) {
  const float* v  = (const float*)d_in[0];
  const float* q  = (const float*)d_in[1];
  const float* k  = (const float*)d_in[2];
  const int* vm   = (const int*)d_in[3];
  const int* qm   = (const int*)d_in[4];
  const int* km   = (const int*)d_in[5];
  const float* Wv = (const float*)d_in[6];
  const float* bv = (const float*)d_in[7];
  const float* Wq = (const float*)d_in[8];
  const float* bq = (const float*)d_in[9];
  const float* Wk = (const float*)d_in[10];
  const float* bk = (const float*)d_in[11];
  const float* Wvo = (const float*)d_in[12];
  const float* bvo = (const float*)d_in[13];
  const float* Wko = (const float*)d_in[14];
  const float* bko = (const float*)d_in[15];
  char* ws = (char*)d_ws;
  float* out = (float*)d_out;

  // Phase A: split/tiling converts for projections
  prep_act<<<dim3(2048, 1, 3), 256, 0, stream>>>(v, q, k, ws, 1,
      O_VR_H, O_VR_L, O_QR_H, O_QR_L, O_KR_H, O_KR_L);
  prep_w<<<dim3(32, 8, 5), 256, 0, stream>>>(Wv, Wq, Wk, ws, 0);
  // Phase B: 5 projection GEMMs (2-MFMA split) -> bf16 row-major
  proj_gemm<<<dim3(1280), 256, 0, stream>>>(ws, bv, bq, bk, vm, qm, km);
  // Phase C: transpose value tensors for PV
  transpose_vt<<<dim3(8, 128, 2), 256, 0, stream>>>(ws);
  // Phase D: both attentions -> split-tiled O
  attn_kernel<<<dim3(2048), 256, 0, stream>>>(ws, qm, km);
  // Phase E: split/tiling converts for output GEMMs
  prep_act<<<dim3(2048, 1, 1), 256, 0, stream>>>(v, v, v, ws, 0,
      O_V2_H, O_V2_L, O_V2_H, O_V2_L, O_V2_H, O_V2_L);
  prep_w<<<dim3(64, 8, 1), 256, 0, stream>>>(Wvo, Wvo, Wvo, ws, 1);
  prep_w<<<dim3(96, 8, 1), 256, 0, stream>>>(Wko, Wko, Wko, ws, 2);
  // Phase F: output GEMMs -> d_out = [updated_V ; updated_v]
  out_gemm<<<dim3(512), 256, 0, stream>>>(ws, bvo, bko, out);
}